// Round 4
// baseline (161.239 us; speedup 1.0000x reference)
//
#include <hip/hip_runtime.h>
#include <hip/hip_cooperative_groups.h>

namespace cg = cooperative_groups;

#define OBJ_DIM 1024
#define NREL 8
#define NOBJ 4096
#define NPAIRS 65536

// ws layout (floats):
//   Wc   : [0, 16384)           -- 8 x 2048 combined weight W2@W1
//   cvec : [16384, 16392)       -- W2 @ b1   (b2 added in gather)
//   pad  : [16392, 16400)
//   proj : [16400, 16400+65536) -- 4096 x 16: [q<8]=sub-proj, [q>=8]=obj-proj
#define WC_OFF   0
#define CVEC_OFF 16384
#define PROJ_OFF 16400

// ===========================================================================
// Fused cooperative kernel: 256 blocks x 256 threads, 64 KB LDS.
// 256 blocks = 1 block/CU under ANY occupancy accounting -> coop validation
// cannot reject the grid (R3's 512-block coop launch was rejected).
// ===========================================================================
__global__ __launch_bounds__(256) void fused_kernel(
    const float* __restrict__ obj, const int* __restrict__ pairs,
    const float* __restrict__ W1, const float* __restrict__ b1,
    const float* __restrict__ W2, const float* __restrict__ b2,
    float* __restrict__ ws, float* __restrict__ out)
{
    __shared__ float sh[16 * 1024];   // 64 KB: lWc during dot, scratch after

    float* Wc   = ws + WC_OFF;
    float* cvec = ws + CVEC_OFF;
    float* proj = ws + PROJ_OFF;

    const int t = threadIdx.x;
    const int b = blockIdx.x;
    cg::grid_group grid = cg::this_grid();

    // -------- Phase A: Wc = W2@W1, cvec = W2@b1 (atomic k-partials) --------
    {
        const int cblk = b & 7;          // 256-col chunk
        const int kblk = b >> 3;         // [0,32), 32 k each
        const int c  = cblk * 256 + t;
        const int k0 = kblk * 32;

        float acc[NREL];
#pragma unroll
        for (int r = 0; r < NREL; ++r) acc[r] = 0.f;

#pragma unroll 8
        for (int kk = 0; kk < 32; ++kk) {
            const int k = k0 + kk;
            const float w1 = W1[(size_t)k * 2048 + c];   // coalesced
#pragma unroll
            for (int r = 0; r < NREL; ++r)
                acc[r] += W2[r * 1024 + k] * w1;          // uniform -> sgpr
        }
#pragma unroll
        for (int r = 0; r < NREL; ++r)
            atomicAdd(&Wc[r * 2048 + c], acc[r]);

        if (cblk == 0 && t < 32) {
            const int k = k0 + t;
            const float bb = b1[k];
#pragma unroll
            for (int r = 0; r < NREL; ++r) {
                float v = W2[r * 1024 + k] * bb;
                v += __shfl_down(v, 16);
                v += __shfl_down(v, 8);
                v += __shfl_down(v, 4);
                v += __shfl_down(v, 2);
                v += __shfl_down(v, 1);
                if (t == 0) atomicAdd(&cvec[r], v);
            }
        }
    }

    grid.sync();

    // -------- Phase B: proj[n][q] = dot(obj[n], Wc_remap[q]) --------------
    // 16 rows/block, 4 rows/wave; each ds_read_b128 of lWc feeds 4 rows.
    {
        // stage + remap: flat Wc idx f = r*2048 + h*1024 + k -> (h*8+r)*1024+k
#pragma unroll
        for (int i = 0; i < 16; ++i) {
            const int f4 = t + 256 * i;        // float4 index, 0..4095
            const int f  = f4 * 4;
            const int r   = f >> 11;
            const int rem = f & 2047;
            const int h   = rem >> 10;
            const int k   = rem & 1023;
            const float4 v = ((const float4*)Wc)[f4];
            *((float4*)&sh[(h * 8 + r) * 1024 + k]) = v;   // k%4==0, aligned
        }
        __syncthreads();

        const int wave = t >> 6, lane = t & 63;
        const int n0 = b * 16 + wave * 4;

        float4 x[4][4];
#pragma unroll
        for (int r = 0; r < 4; ++r) {
            const float4* xp = (const float4*)(obj + (size_t)(n0 + r) * 1024);
#pragma unroll
            for (int i = 0; i < 4; ++i) x[r][i] = xp[lane + 64 * i];
        }

        float a[4][16];
#pragma unroll
        for (int q = 0; q < 16; ++q) {
            const float4* wq = (const float4*)(sh + q * 1024);
            float s0 = 0.f, s1 = 0.f, s2 = 0.f, s3 = 0.f;
#pragma unroll
            for (int i = 0; i < 4; ++i) {
                const float4 w = wq[lane + 64 * i];   // ds_read_b128
                s0 += w.x*x[0][i].x + w.y*x[0][i].y + w.z*x[0][i].z + w.w*x[0][i].w;
                s1 += w.x*x[1][i].x + w.y*x[1][i].y + w.z*x[1][i].z + w.w*x[1][i].w;
                s2 += w.x*x[2][i].x + w.y*x[2][i].y + w.z*x[2][i].z + w.w*x[2][i].w;
                s3 += w.x*x[3][i].x + w.y*x[3][i].y + w.z*x[3][i].z + w.w*x[3][i].w;
            }
            a[0][q] = s0; a[1][q] = s1; a[2][q] = s2; a[3][q] = s3;
        }
        __syncthreads();   // all waves done reading lWc -> reuse as scratch

        // Two reduce rounds; per round rows {2r,2r+1}: o = localrow*16+q.
        // scr[src_lane*36 + o]: b128 writes conflict-free (canonical phasing),
        // stride-36 reads 2-way aliasing only (free per m136).
        float* scr = sh + wave * 2304;
#pragma unroll
        for (int round = 0; round < 2; ++round) {
#pragma unroll
            for (int q4 = 0; q4 < 16; q4 += 4) {
                *((float4*)&scr[lane * 36 + q4]) =
                    make_float4(a[2*round][q4],   a[2*round][q4+1],
                                a[2*round][q4+2], a[2*round][q4+3]);
                *((float4*)&scr[lane * 36 + 16 + q4]) =
                    make_float4(a[2*round+1][q4],   a[2*round+1][q4+1],
                                a[2*round+1][q4+2], a[2*round+1][q4+3]);
            }
            __syncthreads();
            const int o = lane >> 1, half = lane & 1;
            float s = 0.f;
#pragma unroll 8
            for (int j = 0; j < 32; ++j)
                s += scr[(half * 32 + j) * 36 + o];
            s += __shfl_down(s, 1);
            if (half == 0) {
                const int row = 2 * round + (o >> 4), q = o & 15;
                proj[(size_t)(n0 + row) * 16 + q] = s;
            }
            __syncthreads();
        }
    }

    grid.sync();

    // -------- Phase C: gather (exactly 1 pair per thread) ------------------
    {
        const int p = b * 256 + t;
        const int2 ij = ((const int2*)pairs)[p];

        const float4 c0 = ((const float4*)cvec)[0];
        const float4 c1 = ((const float4*)cvec)[1];
        const float4 d0 = ((const float4*)b2)[0];
        const float4 d1 = ((const float4*)b2)[1];

        const float4* ps = (const float4*)(proj + (size_t)ij.x * 16);
        const float4* po = (const float4*)(proj + (size_t)ij.y * 16 + 8);
        const float4 s0 = ps[0], s1 = ps[1];
        const float4 o0 = po[0], o1 = po[1];

        float4 r0, r1;
        r0.x = s0.x + o0.x + c0.x + d0.x;
        r0.y = s0.y + o0.y + c0.y + d0.y;
        r0.z = s0.z + o0.z + c0.z + d0.z;
        r0.w = s0.w + o0.w + c0.w + d0.w;
        r1.x = s1.x + o1.x + c1.x + d1.x;
        r1.y = s1.y + o1.y + c1.y + d1.y;
        r1.z = s1.z + o1.z + c1.z + d1.z;
        r1.w = s1.w + o1.w + c1.w + d1.w;

        ((float4*)out)[(size_t)p * 2]     = r0;
        ((float4*)out)[(size_t)p * 2 + 1] = r1;
    }
}

// ===========================================================================
// Fallback path (R2's verified 3-kernel pipeline) — used if the cooperative
// launch is rejected by the runtime. Identical math.
// ===========================================================================
__global__ __launch_bounds__(256) void prep_kernel(
    const float* __restrict__ W1, const float* __restrict__ W2,
    const float* __restrict__ b1, float* __restrict__ Wc,
    float* __restrict__ cvec)
{
    const int cblk = blockIdx.x & 7;
    const int kblk = blockIdx.x >> 3;
    const int c  = cblk * 256 + threadIdx.x;
    const int k0 = kblk * 32;

    float acc[NREL];
#pragma unroll
    for (int r = 0; r < NREL; ++r) acc[r] = 0.f;

#pragma unroll 8
    for (int kk = 0; kk < 32; ++kk) {
        const int k = k0 + kk;
        const float w1 = W1[(size_t)k * 2048 + c];
#pragma unroll
        for (int r = 0; r < NREL; ++r)
            acc[r] += W2[r * 1024 + k] * w1;
    }
#pragma unroll
    for (int r = 0; r < NREL; ++r)
        atomicAdd(&Wc[r * 2048 + c], acc[r]);

    if (cblk == 0 && threadIdx.x < 32) {
        const int k = k0 + (int)threadIdx.x;
        const float bb = b1[k];
#pragma unroll
        for (int r = 0; r < NREL; ++r) {
            float v = W2[r * 1024 + k] * bb;
            v += __shfl_down(v, 16);
            v += __shfl_down(v, 8);
            v += __shfl_down(v, 4);
            v += __shfl_down(v, 2);
            v += __shfl_down(v, 1);
            if (threadIdx.x == 0) atomicAdd(&cvec[r], v);
        }
    }
}

__global__ __launch_bounds__(256) void proj_kernel(
    const float* __restrict__ obj, const float* __restrict__ Wc,
    float* __restrict__ proj)
{
    __shared__ float sh[16 * 1024];

    const int t = threadIdx.x;
#pragma unroll
    for (int i = 0; i < 16; ++i) {
        const int f4 = t + 256 * i;
        const int f  = f4 * 4;
        const int r   = f >> 11;
        const int rem = f & 2047;
        const int h   = rem >> 10;
        const int k   = rem & 1023;
        const float4 v = ((const float4*)Wc)[f4];
        *((float4*)&sh[(h * 8 + r) * 1024 + k]) = v;
    }
    __syncthreads();

    const int wave = t >> 6, lane = t & 63;
    const int n0 = blockIdx.x * 8 + wave * 2;
    const float4* xa = (const float4*)(obj + (size_t)n0 * 1024);
    const float4* xb = xa + 256;

    float4 x0[4], x1[4];
#pragma unroll
    for (int i = 0; i < 4; ++i) {
        x0[i] = xa[lane + 64 * i];
        x1[i] = xb[lane + 64 * i];
    }

    float a0[16], a1[16];
#pragma unroll
    for (int q = 0; q < 16; ++q) {
        float s0 = 0.f, s1 = 0.f;
        const float4* wq = (const float4*)(sh + q * 1024);
#pragma unroll
        for (int i = 0; i < 4; ++i) {
            const float4 w = wq[lane + 64 * i];
            s0 += w.x * x0[i].x + w.y * x0[i].y + w.z * x0[i].z + w.w * x0[i].w;
            s1 += w.x * x1[i].x + w.y * x1[i].y + w.z * x1[i].z + w.w * x1[i].w;
        }
        a0[q] = s0;
        a1[q] = s1;
    }
    __syncthreads();

    float* scr = sh + wave * 2304;
#pragma unroll
    for (int q4 = 0; q4 < 16; q4 += 4) {
        float4 w0 = make_float4(a0[q4], a0[q4+1], a0[q4+2], a0[q4+3]);
        float4 w1 = make_float4(a1[q4], a1[q4+1], a1[q4+2], a1[q4+3]);
        *((float4*)&scr[lane * 36 + q4])      = w0;
        *((float4*)&scr[lane * 36 + 16 + q4]) = w1;
    }
    __syncthreads();

    const int o = lane >> 1, half = lane & 1;
    float s = 0.f;
#pragma unroll 8
    for (int j = 0; j < 32; ++j)
        s += scr[(half * 32 + j) * 36 + o];
    s += __shfl_down(s, 1);
    if (half == 0) {
        const int row = o >> 4, q = o & 15;
        proj[(size_t)(n0 + row) * 16 + q] = s;
    }
}

__global__ __launch_bounds__(256) void gather_kernel(
    const int* __restrict__ pairs, const float* __restrict__ proj,
    const float* __restrict__ cvec, const float* __restrict__ b2,
    float* __restrict__ out)
{
    const int p = blockIdx.x * 256 + threadIdx.x;

    const int2 ij = ((const int2*)pairs)[p];

    const float4 c0 = ((const float4*)cvec)[0];
    const float4 c1 = ((const float4*)cvec)[1];
    const float4 d0 = ((const float4*)b2)[0];
    const float4 d1 = ((const float4*)b2)[1];

    const float4* ps = (const float4*)(proj + (size_t)ij.x * 16);
    const float4* po = (const float4*)(proj + (size_t)ij.y * 16 + 8);
    const float4 s0 = ps[0], s1 = ps[1];
    const float4 o0 = po[0], o1 = po[1];

    float4 r0, r1;
    r0.x = s0.x + o0.x + c0.x + d0.x;
    r0.y = s0.y + o0.y + c0.y + d0.y;
    r0.z = s0.z + o0.z + c0.z + d0.z;
    r0.w = s0.w + o0.w + c0.w + d0.w;
    r1.x = s1.x + o1.x + c1.x + d1.x;
    r1.y = s1.y + o1.y + c1.y + d1.y;
    r1.z = s1.z + o1.z + c1.z + d1.z;
    r1.w = s1.w + o1.w + c1.w + d1.w;

    ((float4*)out)[(size_t)p * 2]     = r0;
    ((float4*)out)[(size_t)p * 2 + 1] = r1;
}

extern "C" void kernel_launch(void* const* d_in, const int* in_sizes, int n_in,
                              void* d_out, int out_size, void* d_ws, size_t ws_size,
                              hipStream_t stream) {
    const float* obj   = (const float*)d_in[0];   // 4096 x 1024
    const int*   pairs = (const int*)d_in[1];     // 65536 x 2 (int32)
    const float* W1    = (const float*)d_in[2];   // 1024 x 2048
    const float* b1    = (const float*)d_in[3];   // 1024
    const float* W2    = (const float*)d_in[4];   // 8 x 1024
    const float* b2    = (const float*)d_in[5];   // 8
    float* out = (float*)d_out;
    float* ws  = (float*)d_ws;

    // zero the atomic-accumulated regions (ws is poisoned 0xAA before each call)
    hipMemsetAsync(ws, 0, (size_t)(CVEC_OFF + 16) * sizeof(float), stream);

    void* args[] = { (void*)&obj, (void*)&pairs, (void*)&W1, (void*)&b1,
                     (void*)&W2, (void*)&b2, (void*)&ws, (void*)&out };
    hipError_t err = hipLaunchCooperativeKernel((const void*)fused_kernel,
                                                dim3(256), dim3(256), args,
                                                0, stream);
    if (err != hipSuccess) {
        // Coop launch rejected (as in R3 at 512 blocks): run the verified
        // 3-kernel pipeline instead — identical math, same work every call.
        float* Wc   = ws + WC_OFF;
        float* cvec = ws + CVEC_OFF;
        float* proj = ws + PROJ_OFF;
        prep_kernel<<<256, 256, 0, stream>>>(W1, W2, b1, Wc, cvec);
        proj_kernel<<<512, 256, 0, stream>>>(obj, Wc, proj);
        gather_kernel<<<NPAIRS / 256, 256, 0, stream>>>(pairs, proj, cvec, b2, out);
    }
}

// Round 5
// 95.021 us; speedup vs baseline: 1.6969x; 1.6969x over previous
//
#include <hip/hip_runtime.h>

#define OBJ_DIM 1024
#define NREL 8
#define NOBJ 4096
#define NPAIRS 65536

// ws layout (floats):
//   Wc   : [0, 16384)           -- 8 x 2048 combined weight W2@W1
//   cvec : [16384, 16392)       -- W2 @ b1   (b2 added in gather)
//   pad  : [16392, 16400)
//   proj : [16400, 16400+65536) -- 4096 x 16: [q<8]=sub-proj, [q>=8]=obj-proj
#define WC_OFF   0
#define CVEC_OFF 16384
#define PROJ_OFF 16400

// NOTE (R4 post-mortem): cooperative fusion of these three kernels regressed
// 97 -> 161 us. grid.sync() on gfx950 costs ~25+ us each (device-scope fence
// + L2 writeback across 8 non-coherent XCDs); stream-ordered kernel
// boundaries are strictly cheaper here. Keep the 3-kernel pipeline.

// ---------------------------------------------------------------------------
// Kernel A: Wc = W2 @ W1  (8 x 2048), cvec = W2 @ b1 (8)
// grid = 256 blocks: cblk = b & 7 (256 cols each), kblk = b >> 3 (32 k each).
// Wc/cvec zeroed by the memset node; float atomics accumulate k-partials.
// W1 (8 MB) is read exactly once, coalesced. 256 blocks -> all CUs busy.
// ---------------------------------------------------------------------------
__global__ __launch_bounds__(256) void prep_kernel(
    const float* __restrict__ W1, const float* __restrict__ W2,
    const float* __restrict__ b1, float* __restrict__ Wc,
    float* __restrict__ cvec)
{
    const int cblk = blockIdx.x & 7;
    const int kblk = blockIdx.x >> 3;   // [0,32)
    const int c  = cblk * 256 + threadIdx.x;
    const int k0 = kblk * 32;

    float acc[NREL];
#pragma unroll
    for (int r = 0; r < NREL; ++r) acc[r] = 0.f;

#pragma unroll 8
    for (int kk = 0; kk < 32; ++kk) {
        const int k = k0 + kk;
        const float w1 = W1[(size_t)k * 2048 + c];   // coalesced across lanes
#pragma unroll
        for (int r = 0; r < NREL; ++r)
            acc[r] += W2[r * 1024 + k] * w1;          // uniform -> scalar load
    }
#pragma unroll
    for (int r = 0; r < NREL; ++r)
        atomicAdd(&Wc[r * 2048 + c], acc[r]);

    // cvec partials: lanes 0..31 of wave 0 in cblk==0 blocks (k-chunk = 32)
    if (cblk == 0 && threadIdx.x < 32) {
        const int k = k0 + (int)threadIdx.x;
        const float bb = b1[k];
#pragma unroll
        for (int r = 0; r < NREL; ++r) {
            float v = W2[r * 1024 + k] * bb;
            v += __shfl_down(v, 16);
            v += __shfl_down(v, 8);
            v += __shfl_down(v, 4);
            v += __shfl_down(v, 2);
            v += __shfl_down(v, 1);
            if (threadIdx.x == 0) atomicAdd(&cvec[r], v);
        }
    }
}

// ---------------------------------------------------------------------------
// Kernel B: proj[n][q] = dot(obj_feats[n], lWc[q]), q in [0,16)
//   lWc[q][k] = Wc[q][k]        for q < 8   (sub half)
//   lWc[q][k] = Wc[q-8][1024+k] for q >= 8  (obj half)
// One block = 8 rows (2 rows per wave). Wc staged once per block into 64 KB
// LDS (2 blocks/CU, 8 waves/CU). Dot phase uses ds_read_b128 (4 per q, shared
// by both rows). Cross-lane reduction via LDS transpose into the SAME 64 KB
// region (reused as scratch after a barrier): stride-36 layout gives
// conflict-free writes (canonical b128 phasing) and 2-way-only read aliasing.
// grid = 512 blocks x 256 threads.
// ---------------------------------------------------------------------------
__global__ __launch_bounds__(256) void proj_kernel(
    const float* __restrict__ obj, const float* __restrict__ Wc,
    float* __restrict__ proj)
{
    __shared__ float sh[16 * 1024];   // 64 KB: lWc during dot, scratch after

    const int t = threadIdx.x;
    // stage + remap: flat Wc index f = r*2048 + h*1024 + k -> (h*8+r)*1024 + k
#pragma unroll
    for (int i = 0; i < 16; ++i) {
        const int f4 = t + 256 * i;        // float4 index, 0..4095
        const int f  = f4 * 4;
        const int r   = f >> 11;
        const int rem = f & 2047;
        const int h   = rem >> 10;
        const int k   = rem & 1023;
        const float4 v = ((const float4*)Wc)[f4];
        *((float4*)&sh[(h * 8 + r) * 1024 + k]) = v;   // k % 4 == 0, aligned
    }
    __syncthreads();

    const int wave = t >> 6, lane = t & 63;
    const int n0 = blockIdx.x * 8 + wave * 2;
    const float4* xa = (const float4*)(obj + (size_t)n0 * 1024);
    const float4* xb = xa + 256;

    float4 x0[4], x1[4];
#pragma unroll
    for (int i = 0; i < 4; ++i) {
        x0[i] = xa[lane + 64 * i];   // 1 KB/instr, coalesced
        x1[i] = xb[lane + 64 * i];
    }

    float a0[16], a1[16];
#pragma unroll
    for (int q = 0; q < 16; ++q) {
        float s0 = 0.f, s1 = 0.f;
        const float4* wq = (const float4*)(sh + q * 1024);
#pragma unroll
        for (int i = 0; i < 4; ++i) {
            const float4 w = wq[lane + 64 * i];   // ds_read_b128
            s0 += w.x * x0[i].x + w.y * x0[i].y + w.z * x0[i].z + w.w * x0[i].w;
            s1 += w.x * x1[i].x + w.y * x1[i].y + w.z * x1[i].z + w.w * x1[i].w;
        }
        a0[q] = s0;
        a1[q] = s1;
    }
    __syncthreads();   // everyone done reading lWc -> safe to reuse as scratch

    // per-wave private scratch: scr[src_lane*36 + o], o = row*16+q in [0,32)
    float* scr = sh + wave * 2304;           // 63*36+32 = 2300 floats needed
#pragma unroll
    for (int q4 = 0; q4 < 16; q4 += 4) {
        float4 w0 = make_float4(a0[q4], a0[q4 + 1], a0[q4 + 2], a0[q4 + 3]);
        float4 w1 = make_float4(a1[q4], a1[q4 + 1], a1[q4 + 2], a1[q4 + 3]);
        *((float4*)&scr[lane * 36 + q4])      = w0;   // row 0: o = q
        *((float4*)&scr[lane * 36 + 16 + q4]) = w1;   // row 1: o = 16+q
    }
    __syncthreads();   // order write->read (wave-private data; barrier = safe)

    const int o = lane >> 1, half = lane & 1;
    float s = 0.f;
#pragma unroll 8
    for (int j = 0; j < 32; ++j)
        s += scr[(half * 32 + j) * 36 + o];   // banks (4j+o)%32: 2-way only
    s += __shfl_down(s, 1);
    if (half == 0) {
        const int row = o >> 4, q = o & 15;
        proj[(size_t)(n0 + row) * 16 + q] = s;
    }
}

// ---------------------------------------------------------------------------
// Kernel C: out[p][r] = proj[i][r] + proj[j][8+r] + cvec[r] + b2[r]
// One thread per pair; proj table (256 KB) is L2-resident after kernel B.
// ---------------------------------------------------------------------------
__global__ __launch_bounds__(256) void gather_kernel(
    const int* __restrict__ pairs, const float* __restrict__ proj,
    const float* __restrict__ cvec, const float* __restrict__ b2,
    float* __restrict__ out)
{
    const int p = blockIdx.x * 256 + threadIdx.x;

    const int2 ij = ((const int2*)pairs)[p];

    const float4 c0 = ((const float4*)cvec)[0];
    const float4 c1 = ((const float4*)cvec)[1];
    const float4 d0 = ((const float4*)b2)[0];
    const float4 d1 = ((const float4*)b2)[1];

    const float4* ps = (const float4*)(proj + (size_t)ij.x * 16);
    const float4* po = (const float4*)(proj + (size_t)ij.y * 16 + 8);
    const float4 s0 = ps[0], s1 = ps[1];
    const float4 o0 = po[0], o1 = po[1];

    float4 r0, r1;
    r0.x = s0.x + o0.x + c0.x + d0.x;
    r0.y = s0.y + o0.y + c0.y + d0.y;
    r0.z = s0.z + o0.z + c0.z + d0.z;
    r0.w = s0.w + o0.w + c0.w + d0.w;
    r1.x = s1.x + o1.x + c1.x + d1.x;
    r1.y = s1.y + o1.y + c1.y + d1.y;
    r1.z = s1.z + o1.z + c1.z + d1.z;
    r1.w = s1.w + o1.w + c1.w + d1.w;

    ((float4*)out)[(size_t)p * 2]     = r0;
    ((float4*)out)[(size_t)p * 2 + 1] = r1;
}

extern "C" void kernel_launch(void* const* d_in, const int* in_sizes, int n_in,
                              void* d_out, int out_size, void* d_ws, size_t ws_size,
                              hipStream_t stream) {
    const float* obj   = (const float*)d_in[0];   // 4096 x 1024
    const int*   pairs = (const int*)d_in[1];     // 65536 x 2
    const float* W1    = (const float*)d_in[2];   // 1024 x 2048
    const float* b1    = (const float*)d_in[3];   // 1024
    const float* W2    = (const float*)d_in[4];   // 8 x 1024
    const float* b2    = (const float*)d_in[5];   // 8
    float* out = (float*)d_out;

    float* ws   = (float*)d_ws;
    float* Wc   = ws + WC_OFF;
    float* cvec = ws + CVEC_OFF;
    float* proj = ws + PROJ_OFF;

    // zero the atomic-accumulated regions (ws is poisoned 0xAA before each call)
    hipMemsetAsync(ws, 0, (size_t)(CVEC_OFF + 16) * sizeof(float), stream);

    prep_kernel<<<256, 256, 0, stream>>>(W1, W2, b1, Wc, cvec);
    proj_kernel<<<512, 256, 0, stream>>>(obj, Wc, proj);
    gather_kernel<<<NPAIRS / 256, 256, 0, stream>>>(pairs, proj, cvec, b2, out);
}